// Round 1
// baseline (1562.420 us; speedup 1.0000x reference)
//
#include <hip/hip_runtime.h>
#include <math.h>

// ---------------------------------------------------------------------------
// MessageGenerator: edge-softmax attention message passing + MLP head.
// N=20000 nodes, E=200000 edges, D=512, Dm=256, Dh=128, H=512 (fp32).
// ---------------------------------------------------------------------------

__global__ void gate_max_kernel(const float* __restrict__ gate,
                                unsigned int* __restrict__ m_out, int E) {
  float v = 0.0f;
  for (int i = blockIdx.x * blockDim.x + threadIdx.x; i < E;
       i += gridDim.x * blockDim.x)
    v = fmaxf(v, gate[i]);
#pragma unroll
  for (int off = 32; off > 0; off >>= 1)
    v = fmaxf(v, __shfl_down(v, off, 64));
  __shared__ float smax[4];
  int lane = threadIdx.x & 63, w = threadIdx.x >> 6;
  if (lane == 0) smax[w] = v;
  __syncthreads();
  if (threadIdx.x == 0) {
    float bm = fmaxf(fmaxf(smax[0], smax[1]), fmaxf(smax[2], smax[3]));
    // m_out initialized to 0 (== 0.0f). Only positive values matter and for
    // positive floats uint ordering == float ordering -> atomicMax is exact.
    if (bm > 0.0f) atomicMax(m_out, __float_as_uint(bm));
  }
}

__global__ void edge_exp_kernel(const float* __restrict__ gate,
                                const int* __restrict__ idx,
                                const float* __restrict__ m_ptr,
                                float* __restrict__ exp_e,
                                float* __restrict__ row_sum, int E) {
  int e = blockIdx.x * blockDim.x + threadIdx.x;
  if (e >= E) return;
  float m = *m_ptr;
  float v = expf(gate[e] - m);
  exp_e[e] = v;
  atomicAdd(&row_sum[idx[2 * e]], v);
}

// Each block: 4 edges, 64 lanes per edge, 4 floats per lane (Dm = 256).
// msg layout: [N][512] with out0 in cols 0..255 and out1 in cols 256..511
// (the reference's concatenate is free).
__global__ void edge_scatter_kernel(const int* __restrict__ idx,
                                    const float* __restrict__ exp_e,
                                    const float* __restrict__ row_sum,
                                    const float* __restrict__ Mfeat,
                                    float* __restrict__ msg, int E) {
  int e = blockIdx.x * 4 + (threadIdx.x >> 6);
  if (e >= E) return;
  int lane = threadIdx.x & 63;
  int src = idx[2 * e], dst = idx[2 * e + 1];
  float a = exp_e[e] / (row_sum[src] + 1e-6f);
  float4 md = *(const float4*)(Mfeat + (size_t)dst * 256 + lane * 4);
  float4 ms = *(const float4*)(Mfeat + (size_t)src * 256 + lane * 4);
  float* p0 = msg + (size_t)src * 512 + lane * 4;
  atomicAdd(p0 + 0, a * md.x);
  atomicAdd(p0 + 1, a * md.y);
  atomicAdd(p0 + 2, a * md.z);
  atomicAdd(p0 + 3, a * md.w);
  float* p1 = msg + (size_t)dst * 512 + 256 + lane * 4;
  atomicAdd(p1 + 0, a * ms.x);
  atomicAdd(p1 + 1, a * ms.y);
  atomicAdd(p1 + 2, a * ms.z);
  atomicAdd(p1 + 3, a * ms.w);
}

// C[M,N] = A[M,K] @ B[K,N] + bias[N]; EPI==1 adds relu + row validity mask.
// 64x64 tile, BK=16, 256 threads, 4x4 microtile. N, K multiples of 64/16.
template <int EPI>
__global__ __launch_bounds__(256) void gemm_kernel(
    const float* __restrict__ A, const float* __restrict__ B,
    const float* __restrict__ bias, const float* __restrict__ row_sum,
    float* __restrict__ C, int M, int N, int K) {
  __shared__ float As[16][64];  // As[k][m] (transposed store)
  __shared__ float Bs[16][64];  // Bs[k][n]
  int tid = threadIdx.x;
  int tx = tid & 15, ty = tid >> 4;
  int m0 = blockIdx.x * 64, n0 = blockIdx.y * 64;
  float acc[4][4] = {{0.f}};
  for (int k0 = 0; k0 < K; k0 += 16) {
    int ar = tid >> 2, ac = (tid & 3) << 2;
    float4 av;
    if (m0 + ar < M)
      av = *(const float4*)(A + (size_t)(m0 + ar) * K + k0 + ac);
    else
      av = make_float4(0.f, 0.f, 0.f, 0.f);
    As[ac + 0][ar] = av.x;
    As[ac + 1][ar] = av.y;
    As[ac + 2][ar] = av.z;
    As[ac + 3][ar] = av.w;
    int br = tid >> 4, bc = (tid & 15) << 2;
    *(float4*)(&Bs[br][bc]) = *(const float4*)(B + (size_t)(k0 + br) * N + n0 + bc);
    __syncthreads();
#pragma unroll
    for (int k = 0; k < 16; ++k) {
      float4 a4 = *(const float4*)(&As[k][ty << 2]);
      float4 b4 = *(const float4*)(&Bs[k][tx << 2]);
      float aa[4] = {a4.x, a4.y, a4.z, a4.w};
      float bb[4] = {b4.x, b4.y, b4.z, b4.w};
#pragma unroll
      for (int i = 0; i < 4; ++i)
#pragma unroll
        for (int j = 0; j < 4; ++j) acc[i][j] = fmaf(aa[i], bb[j], acc[i][j]);
    }
    __syncthreads();
  }
#pragma unroll
  for (int i = 0; i < 4; ++i) {
    int gm = m0 + (ty << 2) + i;
    if (gm >= M) continue;
    bool valid = true;
    if (EPI == 1) valid = (row_sum[gm] > 0.0f);
#pragma unroll
    for (int j = 0; j < 4; ++j) {
      int gn = n0 + (tx << 2) + j;
      float v = acc[i][j] + bias[gn];
      if (EPI == 1) v = valid ? fmaxf(v, 0.0f) : 0.0f;
      C[(size_t)gm * N + gn] = v;
    }
  }
}

// One 128-thread block per node: layernorm over 128 features + relu, in place.
__global__ void ln_relu_kernel(float* __restrict__ h1,
                               const float* __restrict__ gamma,
                               const float* __restrict__ beta) {
  int n = blockIdx.x;
  int t = threadIdx.x;  // 0..127
  float x = h1[(size_t)n * 128 + t];
  float s1 = x, s2 = x * x;
#pragma unroll
  for (int off = 32; off > 0; off >>= 1) {
    s1 += __shfl_down(s1, off, 64);
    s2 += __shfl_down(s2, off, 64);
  }
  __shared__ float sh[4];
  if ((t & 63) == 0) {
    sh[(t >> 6) * 2 + 0] = s1;
    sh[(t >> 6) * 2 + 1] = s2;
  }
  __syncthreads();
  float tot1 = sh[0] + sh[2], tot2 = sh[1] + sh[3];
  float mu = tot1 * 0.0078125f;            // /128
  float var = tot2 * 0.0078125f - mu * mu; // E[x^2]-mu^2
  float y = (x - mu) * rsqrtf(var + 1e-5f) * gamma[t] + beta[t];
  h1[(size_t)n * 128 + t] = fmaxf(y, 0.0f);
}

extern "C" void kernel_launch(void* const* d_in, const int* in_sizes, int n_in,
                              void* d_out, int out_size, void* d_ws,
                              size_t ws_size, hipStream_t stream) {
  const float* src_feat = (const float*)d_in[0];
  const float* gate = (const float*)d_in[1];
  const int* idx = (const int*)d_in[2];
  const float* Wm = (const float*)d_in[3];
  const float* bm = (const float*)d_in[4];
  const float* W1 = (const float*)d_in[5];
  const float* b1 = (const float*)d_in[6];
  const float* gamma = (const float*)d_in[7];
  const float* beta = (const float*)d_in[8];
  const float* W2 = (const float*)d_in[9];
  const float* b2 = (const float*)d_in[10];
  float* out = (float*)d_out;

  const int D = 512;
  const int Nn = in_sizes[0] / D;  // 20000
  const int E = in_sizes[1];       // 200000

  char* ws = (char*)d_ws;
  size_t off = 0;
  auto alloc = [&](size_t bytes) {
    void* p = ws + off;
    off = (off + bytes + 255) & ~(size_t)255;
    return p;
  };
  unsigned int* m_ptr = (unsigned int*)alloc(4);
  float* exp_e = (float*)alloc((size_t)E * 4);
  float* row_sum = (float*)alloc((size_t)Nn * 4);
  float* Mfeat = (float*)alloc((size_t)Nn * 256 * 4);
  float* msg = (float*)alloc((size_t)Nn * 512 * 4);
  float* h1 = (float*)alloc((size_t)Nn * 128 * 4);

  hipMemsetAsync(m_ptr, 0, 4, stream);
  hipMemsetAsync(row_sum, 0, (size_t)Nn * 4, stream);
  hipMemsetAsync(msg, 0, (size_t)Nn * 512 * 4, stream);

  gate_max_kernel<<<208, 256, 0, stream>>>(gate, m_ptr, E);
  edge_exp_kernel<<<(E + 255) / 256, 256, 0, stream>>>(
      gate, idx, (const float*)m_ptr, exp_e, row_sum, E);
  // Mfeat = src_feat @ Wm + bm   (20000x512 @ 512x256)
  gemm_kernel<0><<<dim3((Nn + 63) / 64, 256 / 64), 256, 0, stream>>>(
      src_feat, Wm, bm, nullptr, Mfeat, Nn, 256, D);
  edge_scatter_kernel<<<(E + 3) / 4, 256, 0, stream>>>(idx, exp_e, row_sum,
                                                       Mfeat, msg, E);
  // h1 = msg @ W1 + b1   (20000x512 @ 512x128)
  gemm_kernel<0><<<dim3((Nn + 63) / 64, 128 / 64), 256, 0, stream>>>(
      msg, W1, b1, nullptr, h1, Nn, 128, D);
  ln_relu_kernel<<<Nn, 128, 0, stream>>>(h1, gamma, beta);
  // out = mask(relu(h1ln @ W2 + b2))   (20000x128 @ 128x512)
  gemm_kernel<1><<<dim3((Nn + 63) / 64, 512 / 64), 256, 0, stream>>>(
      h1, W2, b2, row_sum, out, Nn, 512, 128);
}

// Round 2
// 391.357 us; speedup vs baseline: 3.9923x; 3.9923x over previous
//
#include <hip/hip_runtime.h>
#include <math.h>

// ---------------------------------------------------------------------------
// MessageGenerator: edge-softmax attention message passing + MLP head.
// N=20000 nodes, E=200000 edges, D=512, Dm=256, Dh=128, H=512 (fp32).
// R1: scatter -> CSR + gather (kills 102M fp32 atomics that were 86% of R0).
// ---------------------------------------------------------------------------

__global__ void gate_max_kernel(const float* __restrict__ gate,
                                unsigned int* __restrict__ m_out, int E) {
  float v = 0.0f;
  for (int i = blockIdx.x * blockDim.x + threadIdx.x; i < E;
       i += gridDim.x * blockDim.x)
    v = fmaxf(v, gate[i]);
#pragma unroll
  for (int off = 32; off > 0; off >>= 1)
    v = fmaxf(v, __shfl_down(v, off, 64));
  __shared__ float smax[4];
  int lane = threadIdx.x & 63, w = threadIdx.x >> 6;
  if (lane == 0) smax[w] = v;
  __syncthreads();
  if (threadIdx.x == 0) {
    float bm = fmaxf(fmaxf(smax[0], smax[1]), fmaxf(smax[2], smax[3]));
    // m_out zero-initialized; for positive floats uint order == float order.
    if (bm > 0.0f) atomicMax(m_out, __float_as_uint(bm));
  }
}

// exp(gate-m), row_sum by src, and degree histograms for both CSRs.
__global__ void edge_exp_kernel(const float* __restrict__ gate,
                                const int* __restrict__ idx,
                                const float* __restrict__ m_ptr,
                                float* __restrict__ exp_e,
                                float* __restrict__ row_sum,
                                int* __restrict__ deg_src,
                                int* __restrict__ deg_dst, int E) {
  int e = blockIdx.x * blockDim.x + threadIdx.x;
  if (e >= E) return;
  float m = *m_ptr;
  float v = expf(gate[e] - m);
  exp_e[e] = v;
  int s = idx[2 * e], d = idx[2 * e + 1];
  atomicAdd(&row_sum[s], v);
  atomicAdd(&deg_src[s], 1);
  atomicAdd(&deg_dst[d], 1);
}

// Single-block exclusive scan of two degree arrays -> CSR offsets (n=20000).
__global__ __launch_bounds__(1024) void scan2_kernel(
    const int* __restrict__ degA, const int* __restrict__ degB,
    int* __restrict__ offA, int* __restrict__ offB, int n) {
  __shared__ int tA[1024], tB[1024];
  __shared__ int carryA, carryB;
  if (threadIdx.x == 0) { carryA = 0; carryB = 0; }
  __syncthreads();
  for (int base = 0; base < n; base += 1024) {
    int i = base + threadIdx.x;
    int vA = (i < n) ? degA[i] : 0;
    int vB = (i < n) ? degB[i] : 0;
    tA[threadIdx.x] = vA;
    tB[threadIdx.x] = vB;
    __syncthreads();
    for (int off = 1; off < 1024; off <<= 1) {
      int xA = (threadIdx.x >= off) ? tA[threadIdx.x - off] : 0;
      int xB = (threadIdx.x >= off) ? tB[threadIdx.x - off] : 0;
      __syncthreads();
      tA[threadIdx.x] += xA;
      tB[threadIdx.x] += xB;
      __syncthreads();
    }
    if (i < n) {
      offA[i] = carryA + tA[threadIdx.x] - vA;  // exclusive
      offB[i] = carryB + tB[threadIdx.x] - vB;
    }
    __syncthreads();
    if (threadIdx.x == 0) {
      carryA += tA[1023];
      carryB += tB[1023];
    }
    __syncthreads();
  }
  if (threadIdx.x == 0) {
    offA[n] = carryA;
    offB[n] = carryB;
  }
}

__global__ void scatter_ids_kernel(const int* __restrict__ idx,
                                   const int* __restrict__ off_src,
                                   const int* __restrict__ off_dst,
                                   int* __restrict__ cur_src,
                                   int* __restrict__ cur_dst,
                                   int* __restrict__ csr_src,
                                   int* __restrict__ csr_dst, int E) {
  int e = blockIdx.x * blockDim.x + threadIdx.x;
  if (e >= E) return;
  int s = idx[2 * e], d = idx[2 * e + 1];
  int p = atomicAdd(&cur_src[s], 1);
  csr_src[off_src[s] + p] = e;
  int q = atomicAdd(&cur_dst[d], 1);
  csr_dst[off_dst[d] + q] = e;
}

// One wave per node. acc0 = sum_{e: src=n} a_e*Mfeat[dst_e];
// acc1 = sum_{e: dst=n} a_e*Mfeat[src_e]. Writes msg row once (no memset).
__global__ __launch_bounds__(256) void aggregate_kernel(
    const int* __restrict__ idx, const float* __restrict__ exp_e,
    const float* __restrict__ row_sum, const int* __restrict__ off_src,
    const int* __restrict__ csr_src, const int* __restrict__ off_dst,
    const int* __restrict__ csr_dst, const float* __restrict__ Mfeat,
    float* __restrict__ msg, int Nn) {
  int node = blockIdx.x * 4 + (threadIdx.x >> 6);
  if (node >= Nn) return;
  int lane = threadIdx.x & 63;
  float4 acc0 = make_float4(0.f, 0.f, 0.f, 0.f);
  float4 acc1 = make_float4(0.f, 0.f, 0.f, 0.f);
  int b0 = off_src[node], e0 = off_src[node + 1];
  float inv = 1.0f / (row_sum[node] + 1e-6f);
  for (int t = b0; t < e0; ++t) {
    int e = csr_src[t];
    int dst = idx[2 * e + 1];
    float a = exp_e[e] * inv;
    float4 mv = *((const float4*)(Mfeat + (size_t)dst * 256) + lane);
    acc0.x = fmaf(a, mv.x, acc0.x);
    acc0.y = fmaf(a, mv.y, acc0.y);
    acc0.z = fmaf(a, mv.z, acc0.z);
    acc0.w = fmaf(a, mv.w, acc0.w);
  }
  int b1 = off_dst[node], e1 = off_dst[node + 1];
  for (int t = b1; t < e1; ++t) {
    int e = csr_dst[t];
    int src = idx[2 * e];
    float a = exp_e[e] / (row_sum[src] + 1e-6f);
    float4 mv = *((const float4*)(Mfeat + (size_t)src * 256) + lane);
    acc1.x = fmaf(a, mv.x, acc1.x);
    acc1.y = fmaf(a, mv.y, acc1.y);
    acc1.z = fmaf(a, mv.z, acc1.z);
    acc1.w = fmaf(a, mv.w, acc1.w);
  }
  *((float4*)(msg + (size_t)node * 512) + lane) = acc0;
  *((float4*)(msg + (size_t)node * 512 + 256) + lane) = acc1;
}

// C[M,N] = A[M,K] @ B[K,N] + bias[N]; EPI==1 adds relu + row validity mask.
template <int EPI>
__global__ __launch_bounds__(256) void gemm_kernel(
    const float* __restrict__ A, const float* __restrict__ B,
    const float* __restrict__ bias, const float* __restrict__ row_sum,
    float* __restrict__ C, int M, int N, int K) {
  __shared__ float As[16][64];
  __shared__ float Bs[16][64];
  int tid = threadIdx.x;
  int tx = tid & 15, ty = tid >> 4;
  int m0 = blockIdx.x * 64, n0 = blockIdx.y * 64;
  float acc[4][4] = {{0.f}};
  for (int k0 = 0; k0 < K; k0 += 16) {
    int ar = tid >> 2, ac = (tid & 3) << 2;
    float4 av;
    if (m0 + ar < M)
      av = *(const float4*)(A + (size_t)(m0 + ar) * K + k0 + ac);
    else
      av = make_float4(0.f, 0.f, 0.f, 0.f);
    As[ac + 0][ar] = av.x;
    As[ac + 1][ar] = av.y;
    As[ac + 2][ar] = av.z;
    As[ac + 3][ar] = av.w;
    int br = tid >> 4, bc = (tid & 15) << 2;
    *(float4*)(&Bs[br][bc]) = *(const float4*)(B + (size_t)(k0 + br) * N + n0 + bc);
    __syncthreads();
#pragma unroll
    for (int k = 0; k < 16; ++k) {
      float4 a4 = *(const float4*)(&As[k][ty << 2]);
      float4 b4 = *(const float4*)(&Bs[k][tx << 2]);
      float aa[4] = {a4.x, a4.y, a4.z, a4.w};
      float bb[4] = {b4.x, b4.y, b4.z, b4.w};
#pragma unroll
      for (int i = 0; i < 4; ++i)
#pragma unroll
        for (int j = 0; j < 4; ++j) acc[i][j] = fmaf(aa[i], bb[j], acc[i][j]);
    }
    __syncthreads();
  }
#pragma unroll
  for (int i = 0; i < 4; ++i) {
    int gm = m0 + (ty << 2) + i;
    if (gm >= M) continue;
    bool valid = true;
    if (EPI == 1) valid = (row_sum[gm] > 0.0f);
#pragma unroll
    for (int j = 0; j < 4; ++j) {
      int gn = n0 + (tx << 2) + j;
      float v = acc[i][j] + bias[gn];
      if (EPI == 1) v = valid ? fmaxf(v, 0.0f) : 0.0f;
      C[(size_t)gm * N + gn] = v;
    }
  }
}

__global__ void ln_relu_kernel(float* __restrict__ h1,
                               const float* __restrict__ gamma,
                               const float* __restrict__ beta) {
  int n = blockIdx.x;
  int t = threadIdx.x;  // 0..127
  float x = h1[(size_t)n * 128 + t];
  float s1 = x, s2 = x * x;
#pragma unroll
  for (int off = 32; off > 0; off >>= 1) {
    s1 += __shfl_down(s1, off, 64);
    s2 += __shfl_down(s2, off, 64);
  }
  __shared__ float sh[4];
  if ((t & 63) == 0) {
    sh[(t >> 6) * 2 + 0] = s1;
    sh[(t >> 6) * 2 + 1] = s2;
  }
  __syncthreads();
  float tot1 = sh[0] + sh[2], tot2 = sh[1] + sh[3];
  float mu = tot1 * 0.0078125f;
  float var = tot2 * 0.0078125f - mu * mu;
  float y = (x - mu) * rsqrtf(var + 1e-5f) * gamma[t] + beta[t];
  h1[(size_t)n * 128 + t] = fmaxf(y, 0.0f);
}

extern "C" void kernel_launch(void* const* d_in, const int* in_sizes, int n_in,
                              void* d_out, int out_size, void* d_ws,
                              size_t ws_size, hipStream_t stream) {
  const float* src_feat = (const float*)d_in[0];
  const float* gate = (const float*)d_in[1];
  const int* idx = (const int*)d_in[2];
  const float* Wm = (const float*)d_in[3];
  const float* bm = (const float*)d_in[4];
  const float* W1 = (const float*)d_in[5];
  const float* b1 = (const float*)d_in[6];
  const float* gamma = (const float*)d_in[7];
  const float* beta = (const float*)d_in[8];
  const float* W2 = (const float*)d_in[9];
  const float* b2 = (const float*)d_in[10];
  float* out = (float*)d_out;

  const int D = 512;
  const int Nn = in_sizes[0] / D;  // 20000
  const int E = in_sizes[1];       // 200000

  char* ws = (char*)d_ws;
  size_t off = 0;
  auto alloc = [&](size_t bytes) {
    void* p = ws + off;
    off = (off + bytes + 255) & ~(size_t)255;
    return p;
  };
  unsigned int* m_ptr = (unsigned int*)alloc(4);
  float* exp_e = (float*)alloc((size_t)E * 4);
  float* row_sum = (float*)alloc((size_t)Nn * 4);
  float* Mfeat = (float*)alloc((size_t)Nn * 256 * 4);
  float* msg = (float*)alloc((size_t)Nn * 512 * 4);
  float* h1 = (float*)alloc((size_t)Nn * 128 * 4);  // 10.24 MB

  // CSR scratch overlaid on h1 (h1 is written only by GEMM2, which launches
  // after aggregate_kernel has consumed the CSR -> no lifetime overlap).
  char* ov = (char*)h1;
  size_t ooff = 0;
  auto oalloc = [&](size_t bytes) {
    void* p = ov + ooff;
    ooff = (ooff + bytes + 255) & ~(size_t)255;
    return p;
  };
  int* deg_src = (int*)oalloc((size_t)Nn * 4);
  int* deg_dst = (int*)oalloc((size_t)Nn * 4);
  int* off_src = (int*)oalloc((size_t)(Nn + 1) * 4);
  int* off_dst = (int*)oalloc((size_t)(Nn + 1) * 4);
  int* cur_src = (int*)oalloc((size_t)Nn * 4);
  int* cur_dst = (int*)oalloc((size_t)Nn * 4);
  int* csr_src = (int*)oalloc((size_t)E * 4);
  int* csr_dst = (int*)oalloc((size_t)E * 4);

  hipMemsetAsync(m_ptr, 0, 4, stream);
  hipMemsetAsync(row_sum, 0, (size_t)Nn * 4, stream);
  hipMemsetAsync(deg_src, 0, (size_t)Nn * 4, stream);
  hipMemsetAsync(deg_dst, 0, (size_t)Nn * 4, stream);
  hipMemsetAsync(cur_src, 0, (size_t)Nn * 4, stream);
  hipMemsetAsync(cur_dst, 0, (size_t)Nn * 4, stream);

  gate_max_kernel<<<208, 256, 0, stream>>>(gate, m_ptr, E);
  edge_exp_kernel<<<(E + 255) / 256, 256, 0, stream>>>(
      gate, idx, (const float*)m_ptr, exp_e, row_sum, deg_src, deg_dst, E);
  scan2_kernel<<<1, 1024, 0, stream>>>(deg_src, deg_dst, off_src, off_dst, Nn);
  scatter_ids_kernel<<<(E + 255) / 256, 256, 0, stream>>>(
      idx, off_src, off_dst, cur_src, cur_dst, csr_src, csr_dst, E);
  // Mfeat = src_feat @ Wm + bm   (20000x512 @ 512x256)
  gemm_kernel<0><<<dim3((Nn + 63) / 64, 256 / 64), 256, 0, stream>>>(
      src_feat, Wm, bm, nullptr, Mfeat, Nn, 256, D);
  aggregate_kernel<<<(Nn + 3) / 4, 256, 0, stream>>>(
      idx, exp_e, row_sum, off_src, csr_src, off_dst, csr_dst, Mfeat, msg, Nn);
  // h1 = msg @ W1 + b1   (20000x512 @ 512x128)
  gemm_kernel<0><<<dim3((Nn + 63) / 64, 128 / 64), 256, 0, stream>>>(
      msg, W1, b1, nullptr, h1, Nn, 128, D);
  ln_relu_kernel<<<Nn, 128, 0, stream>>>(h1, gamma, beta);
  // out = mask(relu(h1ln @ W2 + b2))   (20000x128 @ 128x512)
  gemm_kernel<1><<<dim3((Nn + 63) / 64, 512 / 64), 256, 0, stream>>>(
      h1, W2, b2, row_sum, out, Nn, 512, 128);
}

// Round 3
// 261.612 us; speedup vs baseline: 5.9723x; 1.4959x over previous
//
#include <hip/hip_runtime.h>
#include <math.h>

// ---------------------------------------------------------------------------
// MessageGenerator: edge-softmax attention message passing + MLP head.
// N=20000 nodes, E=200000 edges, D=512, Dm=256, Dh=128, H=512.
// R1: scatter -> CSR + gather. R2: bf16 MFMA GEMMs + bf16 dataflow.
// ---------------------------------------------------------------------------

typedef __attribute__((ext_vector_type(8))) short short8;
typedef __attribute__((ext_vector_type(4))) float f32x4;

static __device__ __forceinline__ unsigned short f2bf(float f) {
  union { float f; unsigned int u; } v; v.f = f;
  unsigned int r = v.u + 0x7fffu + ((v.u >> 16) & 1u);  // round-nearest-even
  return (unsigned short)(r >> 16);
}
static __device__ __forceinline__ float bf2f(unsigned short b) {
  union { unsigned int u; float f; } v; v.u = ((unsigned int)b) << 16;
  return v.f;
}

__global__ void gate_max_kernel(const float* __restrict__ gate,
                                unsigned int* __restrict__ m_out, int E) {
  float v = 0.0f;
  for (int i = blockIdx.x * blockDim.x + threadIdx.x; i < E;
       i += gridDim.x * blockDim.x)
    v = fmaxf(v, gate[i]);
#pragma unroll
  for (int off = 32; off > 0; off >>= 1)
    v = fmaxf(v, __shfl_down(v, off, 64));
  __shared__ float smax[4];
  int lane = threadIdx.x & 63, w = threadIdx.x >> 6;
  if (lane == 0) smax[w] = v;
  __syncthreads();
  if (threadIdx.x == 0) {
    float bm = fmaxf(fmaxf(smax[0], smax[1]), fmaxf(smax[2], smax[3]));
    if (bm > 0.0f) atomicMax(m_out, __float_as_uint(bm));  // uint order==float order for >0
  }
}

__global__ void edge_exp_kernel(const float* __restrict__ gate,
                                const int* __restrict__ idx,
                                const float* __restrict__ m_ptr,
                                float* __restrict__ exp_e,
                                float* __restrict__ row_sum,
                                int* __restrict__ deg_src,
                                int* __restrict__ deg_dst, int E) {
  int e = blockIdx.x * blockDim.x + threadIdx.x;
  if (e >= E) return;
  float m = *m_ptr;
  float v = expf(gate[e] - m);
  exp_e[e] = v;
  int s = idx[2 * e], d = idx[2 * e + 1];
  atomicAdd(&row_sum[s], v);
  atomicAdd(&deg_src[s], 1);
  atomicAdd(&deg_dst[d], 1);
}

__global__ __launch_bounds__(1024) void scan2_kernel(
    const int* __restrict__ degA, const int* __restrict__ degB,
    int* __restrict__ offA, int* __restrict__ offB, int n) {
  __shared__ int tA[1024], tB[1024];
  __shared__ int carryA, carryB;
  if (threadIdx.x == 0) { carryA = 0; carryB = 0; }
  __syncthreads();
  for (int base = 0; base < n; base += 1024) {
    int i = base + threadIdx.x;
    int vA = (i < n) ? degA[i] : 0;
    int vB = (i < n) ? degB[i] : 0;
    tA[threadIdx.x] = vA;
    tB[threadIdx.x] = vB;
    __syncthreads();
    for (int off = 1; off < 1024; off <<= 1) {
      int xA = (threadIdx.x >= off) ? tA[threadIdx.x - off] : 0;
      int xB = (threadIdx.x >= off) ? tB[threadIdx.x - off] : 0;
      __syncthreads();
      tA[threadIdx.x] += xA;
      tB[threadIdx.x] += xB;
      __syncthreads();
    }
    if (i < n) {
      offA[i] = carryA + tA[threadIdx.x] - vA;
      offB[i] = carryB + tB[threadIdx.x] - vB;
    }
    __syncthreads();
    if (threadIdx.x == 0) {
      carryA += tA[1023];
      carryB += tB[1023];
    }
    __syncthreads();
  }
  if (threadIdx.x == 0) {
    offA[n] = carryA;
    offB[n] = carryB;
  }
}

__global__ void scatter_ids_kernel(const int* __restrict__ idx,
                                   const int* __restrict__ off_src,
                                   const int* __restrict__ off_dst,
                                   int* __restrict__ cur_src,
                                   int* __restrict__ cur_dst,
                                   int* __restrict__ csr_src,
                                   int* __restrict__ csr_dst, int E) {
  int e = blockIdx.x * blockDim.x + threadIdx.x;
  if (e >= E) return;
  int s = idx[2 * e], d = idx[2 * e + 1];
  int p = atomicAdd(&cur_src[s], 1);
  csr_src[off_src[s] + p] = e;
  int q = atomicAdd(&cur_dst[d], 1);
  csr_dst[off_dst[d] + q] = e;
}

// out[n*K+k] = bf16(in[k*N+n])  (weight transpose+convert, tiny)
__global__ void convt_kernel(const float* __restrict__ in,
                             short* __restrict__ out, int K, int N) {
  int i = blockIdx.x * 256 + threadIdx.x;
  if (i >= K * N) return;
  int n = i / K, k = i - n * K;
  out[i] = (short)f2bf(in[(size_t)k * N + n]);
}

// One wave per node, bf16 Mfeat gathers (ushort4/lane = 512B/row), bf16 msg out.
__global__ __launch_bounds__(256) void aggregate_kernel(
    const int* __restrict__ idx, const float* __restrict__ exp_e,
    const float* __restrict__ row_sum, const int* __restrict__ off_src,
    const int* __restrict__ csr_src, const int* __restrict__ off_dst,
    const int* __restrict__ csr_dst, const unsigned short* __restrict__ Mfeat,
    unsigned short* __restrict__ msg, int Nn) {
  int node = blockIdx.x * 4 + (threadIdx.x >> 6);
  if (node >= Nn) return;
  int lane = threadIdx.x & 63;
  float a0x = 0.f, a0y = 0.f, a0z = 0.f, a0w = 0.f;
  float a1x = 0.f, a1y = 0.f, a1z = 0.f, a1w = 0.f;
  float inv = 1.0f / (row_sum[node] + 1e-6f);
  int b0 = off_src[node], e0 = off_src[node + 1];
  for (int base = b0; base < e0; base += 64) {
    int cnt = min(64, e0 - base);
    int eid = (lane < cnt) ? csr_src[base + lane] : 0;
    float aw = (lane < cnt) ? exp_e[eid] : 0.0f;
    int oth = (lane < cnt) ? idx[2 * eid + 1] : 0;
    for (int t = 0; t < cnt; ++t) {
      float a = __shfl(aw, t, 64) * inv;
      int row = __shfl(oth, t, 64);
      ushort4 mv = *((const ushort4*)(Mfeat + (size_t)row * 256) + lane);
      a0x = fmaf(a, bf2f(mv.x), a0x);
      a0y = fmaf(a, bf2f(mv.y), a0y);
      a0z = fmaf(a, bf2f(mv.z), a0z);
      a0w = fmaf(a, bf2f(mv.w), a0w);
    }
  }
  int b1 = off_dst[node], e1 = off_dst[node + 1];
  for (int base = b1; base < e1; base += 64) {
    int cnt = min(64, e1 - base);
    int eid = (lane < cnt) ? csr_dst[base + lane] : 0;
    int s = (lane < cnt) ? idx[2 * eid] : 0;
    float aw = (lane < cnt) ? (exp_e[eid] / (row_sum[s] + 1e-6f)) : 0.0f;
    for (int t = 0; t < cnt; ++t) {
      float a = __shfl(aw, t, 64);
      int row = __shfl(s, t, 64);
      ushort4 mv = *((const ushort4*)(Mfeat + (size_t)row * 256) + lane);
      a1x = fmaf(a, bf2f(mv.x), a1x);
      a1y = fmaf(a, bf2f(mv.y), a1y);
      a1z = fmaf(a, bf2f(mv.z), a1z);
      a1w = fmaf(a, bf2f(mv.w), a1w);
    }
  }
  ushort4 o0, o1;
  o0.x = f2bf(a0x); o0.y = f2bf(a0y); o0.z = f2bf(a0z); o0.w = f2bf(a0w);
  o1.x = f2bf(a1x); o1.y = f2bf(a1y); o1.z = f2bf(a1z); o1.w = f2bf(a1w);
  *((ushort4*)(msg + (size_t)node * 512) + lane) = o0;
  *((ushort4*)(msg + (size_t)node * 512 + 256) + lane) = o1;
}

// bf16 MFMA GEMM: C[M,N] = A[M,K] @ Bt[N,K]^T + bias.
// Tile 128x64, BK=64, 256 threads = 4 waves (2x2), wave tile 64x32,
// 16x16x32 MFMA, XOR-swizzled LDS (T2).
// ABF16: A is bf16 (else fp32, converted in staging).
// OUT_MODE: 0 = f32 +bias; 1 = f32 +bias+relu+valid-mask; 2 = bf16 +bias.
template <int ABF16, int OUT_MODE>
__global__ __launch_bounds__(256) void mfma_gemm_kernel(
    const void* __restrict__ Av, const short* __restrict__ Bt,
    const float* __restrict__ bias, const float* __restrict__ row_sum,
    void* __restrict__ Cv, int M, int N, int K) {
  __shared__ short As[128 * 64];
  __shared__ short Bs[64 * 64];
  int tid = threadIdx.x;
  int lane = tid & 63, wid = tid >> 6;
  int wr = wid >> 1, wc = wid & 1;
  int m0 = blockIdx.x * 128, n0 = blockIdx.y * 64;

  f32x4 acc[4][2];
#pragma unroll
  for (int m = 0; m < 4; ++m)
#pragma unroll
    for (int n = 0; n < 2; ++n) acc[m][n] = (f32x4){0.f, 0.f, 0.f, 0.f};

  int ar = tid >> 1;            // A row 0..127
  int akg = (tid & 1) * 4;      // first 16B group (of 8) in k
  bool arow_ok = (m0 + ar) < M;
  int nr = tid >> 2;            // B row (n) 0..63
  int nkg = (tid & 3) * 2;

  for (int k0 = 0; k0 < K; k0 += 64) {
    if (ABF16) {
      const short8* ap =
          (const short8*)((const short*)Av + (size_t)(m0 + ar) * K + k0 + akg * 8);
#pragma unroll
      for (int g2 = 0; g2 < 4; ++g2) {
        short8 w = (short8){0, 0, 0, 0, 0, 0, 0, 0};
        if (arow_ok) w = ap[g2];
        int g = akg + g2;
        *(short8*)&As[ar * 64 + ((g ^ (ar & 7)) << 3)] = w;
      }
    } else {
      const float4* ap =
          (const float4*)((const float*)Av + (size_t)(m0 + ar) * K + k0 + akg * 8);
#pragma unroll
      for (int g2 = 0; g2 < 4; ++g2) {
        float4 u = make_float4(0.f, 0.f, 0.f, 0.f);
        float4 v = make_float4(0.f, 0.f, 0.f, 0.f);
        if (arow_ok) { u = ap[2 * g2]; v = ap[2 * g2 + 1]; }
        short8 w;
        w[0] = (short)f2bf(u.x); w[1] = (short)f2bf(u.y);
        w[2] = (short)f2bf(u.z); w[3] = (short)f2bf(u.w);
        w[4] = (short)f2bf(v.x); w[5] = (short)f2bf(v.y);
        w[6] = (short)f2bf(v.z); w[7] = (short)f2bf(v.w);
        int g = akg + g2;
        *(short8*)&As[ar * 64 + ((g ^ (ar & 7)) << 3)] = w;
      }
    }
    {
      const short8* bp = (const short8*)(Bt + (size_t)(n0 + nr) * K + k0);
#pragma unroll
      for (int g2 = 0; g2 < 2; ++g2) {
        int g = nkg + g2;
        short8 w = bp[g];
        *(short8*)&Bs[nr * 64 + ((g ^ (nr & 7)) << 3)] = w;
      }
    }
    __syncthreads();
    int lsw = lane & 7, l15 = lane & 15, lk = lane >> 4;
#pragma unroll
    for (int kk = 0; kk < 2; ++kk) {
      int gg = kk * 4 + lk;
      int xo = ((gg ^ lsw) << 3);
      short8 af[4], bf[2];
#pragma unroll
      for (int m = 0; m < 4; ++m)
        af[m] = *(const short8*)&As[(wr * 64 + m * 16 + l15) * 64 + xo];
#pragma unroll
      for (int n = 0; n < 2; ++n)
        bf[n] = *(const short8*)&Bs[(wc * 32 + n * 16 + l15) * 64 + xo];
#pragma unroll
      for (int m = 0; m < 4; ++m)
#pragma unroll
        for (int n = 0; n < 2; ++n)
          acc[m][n] = __builtin_amdgcn_mfma_f32_16x16x32_bf16(af[m], bf[n],
                                                              acc[m][n], 0, 0, 0);
    }
    __syncthreads();
  }
  // epilogue: D row = (lane>>4)*4 + r, col = lane&15
#pragma unroll
  for (int m = 0; m < 4; ++m) {
    int gmBase = m0 + wr * 64 + m * 16 + (lane >> 4) * 4;
#pragma unroll
    for (int n = 0; n < 2; ++n) {
      int gn = n0 + wc * 32 + n * 16 + (lane & 15);
      float bv = bias[gn];
#pragma unroll
      for (int r = 0; r < 4; ++r) {
        int gm = gmBase + r;
        if (gm >= M) continue;
        float v = acc[m][n][r] + bv;
        if (OUT_MODE == 1) v = (row_sum[gm] > 0.0f) ? fmaxf(v, 0.0f) : 0.0f;
        if (OUT_MODE == 2)
          ((unsigned short*)Cv)[(size_t)gm * N + gn] = f2bf(v);
        else
          ((float*)Cv)[(size_t)gm * N + gn] = v;
      }
    }
  }
}

// LN(+relu) over 128 features, fp32 in -> bf16 out.
__global__ void ln_relu_kernel(const float* __restrict__ h1,
                               const float* __restrict__ gamma,
                               const float* __restrict__ beta,
                               unsigned short* __restrict__ h1ln) {
  int n = blockIdx.x;
  int t = threadIdx.x;  // 0..127
  float x = h1[(size_t)n * 128 + t];
  float s1 = x, s2 = x * x;
#pragma unroll
  for (int off = 32; off > 0; off >>= 1) {
    s1 += __shfl_down(s1, off, 64);
    s2 += __shfl_down(s2, off, 64);
  }
  __shared__ float sh[4];
  if ((t & 63) == 0) {
    sh[(t >> 6) * 2 + 0] = s1;
    sh[(t >> 6) * 2 + 1] = s2;
  }
  __syncthreads();
  float tot1 = sh[0] + sh[2], tot2 = sh[1] + sh[3];
  float mu = tot1 * 0.0078125f;
  float var = tot2 * 0.0078125f - mu * mu;
  float y = (x - mu) * rsqrtf(var + 1e-5f) * gamma[t] + beta[t];
  h1ln[(size_t)n * 128 + t] = f2bf(fmaxf(y, 0.0f));
}

extern "C" void kernel_launch(void* const* d_in, const int* in_sizes, int n_in,
                              void* d_out, int out_size, void* d_ws,
                              size_t ws_size, hipStream_t stream) {
  const float* src_feat = (const float*)d_in[0];
  const float* gate = (const float*)d_in[1];
  const int* idx = (const int*)d_in[2];
  const float* Wm = (const float*)d_in[3];
  const float* bm = (const float*)d_in[4];
  const float* W1 = (const float*)d_in[5];
  const float* b1 = (const float*)d_in[6];
  const float* gamma = (const float*)d_in[7];
  const float* beta = (const float*)d_in[8];
  const float* W2 = (const float*)d_in[9];
  const float* b2 = (const float*)d_in[10];
  float* out = (float*)d_out;

  const int D = 512;
  const int Nn = in_sizes[0] / D;  // 20000
  const int E = in_sizes[1];       // 200000

  char* ws = (char*)d_ws;
  size_t off = 0;
  auto alloc = [&](size_t bytes) {
    void* p = ws + off;
    off = (off + bytes + 255) & ~(size_t)255;
    return p;
  };
  unsigned int* m_ptr = (unsigned int*)alloc(4);
  float* exp_e = (float*)alloc((size_t)E * 4);
  float* row_sum = (float*)alloc((size_t)Nn * 4);
  unsigned short* Mfeat = (unsigned short*)alloc((size_t)Nn * 256 * 2);
  unsigned short* msg = (unsigned short*)alloc((size_t)Nn * 512 * 2);
  float* h1 = (float*)alloc((size_t)Nn * 128 * 4);
  unsigned short* h1ln = (unsigned short*)alloc((size_t)Nn * 128 * 2);
  short* WmT = (short*)alloc((size_t)512 * 256 * 2);
  short* W1T = (short*)alloc((size_t)512 * 128 * 2);
  short* W2T = (short*)alloc((size_t)128 * 512 * 2);

  // CSR scratch overlaid on h1 (consumed by aggregate before GEMM2 writes h1).
  char* ov = (char*)h1;
  size_t ooff = 0;
  auto oalloc = [&](size_t bytes) {
    void* p = ov + ooff;
    ooff = (ooff + bytes + 255) & ~(size_t)255;
    return p;
  };
  int* deg_src = (int*)oalloc((size_t)Nn * 4);
  int* deg_dst = (int*)oalloc((size_t)Nn * 4);
  int* off_src = (int*)oalloc((size_t)(Nn + 1) * 4);
  int* off_dst = (int*)oalloc((size_t)(Nn + 1) * 4);
  int* cur_src = (int*)oalloc((size_t)Nn * 4);
  int* cur_dst = (int*)oalloc((size_t)Nn * 4);
  int* csr_src = (int*)oalloc((size_t)E * 4);
  int* csr_dst = (int*)oalloc((size_t)E * 4);

  hipMemsetAsync(m_ptr, 0, 4, stream);
  hipMemsetAsync(row_sum, 0, (size_t)Nn * 4, stream);
  hipMemsetAsync(deg_src, 0, (size_t)Nn * 4, stream);
  hipMemsetAsync(deg_dst, 0, (size_t)Nn * 4, stream);
  hipMemsetAsync(cur_src, 0, (size_t)Nn * 4, stream);
  hipMemsetAsync(cur_dst, 0, (size_t)Nn * 4, stream);

  convt_kernel<<<(512 * 256 + 255) / 256, 256, 0, stream>>>(Wm, WmT, 512, 256);
  convt_kernel<<<(512 * 128 + 255) / 256, 256, 0, stream>>>(W1, W1T, 512, 128);
  convt_kernel<<<(128 * 512 + 255) / 256, 256, 0, stream>>>(W2, W2T, 128, 512);

  gate_max_kernel<<<208, 256, 0, stream>>>(gate, m_ptr, E);
  edge_exp_kernel<<<(E + 255) / 256, 256, 0, stream>>>(
      gate, idx, (const float*)m_ptr, exp_e, row_sum, deg_src, deg_dst, E);
  scan2_kernel<<<1, 1024, 0, stream>>>(deg_src, deg_dst, off_src, off_dst, Nn);
  scatter_ids_kernel<<<(E + 255) / 256, 256, 0, stream>>>(
      idx, off_src, off_dst, cur_src, cur_dst, csr_src, csr_dst, E);

  int gx = (Nn + 127) / 128;  // 157
  // GEMM1: Mfeat(bf16) = src_feat(f32) @ Wm + bm   [M=Nn, N=256, K=512]
  mfma_gemm_kernel<0, 2><<<dim3(gx, 4), 256, 0, stream>>>(
      src_feat, WmT, bm, nullptr, Mfeat, Nn, 256, D);
  aggregate_kernel<<<(Nn + 3) / 4, 256, 0, stream>>>(
      idx, exp_e, row_sum, off_src, csr_src, off_dst, csr_dst, Mfeat, msg, Nn);
  // GEMM2: h1(f32) = msg(bf16) @ W1 + b1   [M=Nn, N=128, K=512]
  mfma_gemm_kernel<1, 0><<<dim3(gx, 2), 256, 0, stream>>>(
      msg, W1T, b1, nullptr, h1, Nn, 128, D);
  ln_relu_kernel<<<Nn, 128, 0, stream>>>(h1, gamma, beta, h1ln);
  // GEMM3: out(f32) = h1ln(bf16) @ W2 + b2, relu+mask   [M=Nn, N=512, K=128]
  mfma_gemm_kernel<1, 1><<<dim3(gx, 8), 256, 0, stream>>>(
      h1ln, W2T, b2, row_sum, out, Nn, 512, 128);
}

// Round 4
// 222.556 us; speedup vs baseline: 7.0204x; 1.1755x over previous
//
#include <hip/hip_runtime.h>
#include <math.h>

// ---------------------------------------------------------------------------
// MessageGenerator: edge-softmax attention message passing + MLP head.
// N=20000 nodes, E=200000 edges, D=512, Dm=256, Dh=128, H=512.
// R1: scatter -> CSR + gather. R2: bf16 MFMA GEMMs + bf16 dataflow.
// R3: multi-block scan (was 49.5us single-block), wave-per-node LN.
// ---------------------------------------------------------------------------

typedef __attribute__((ext_vector_type(8))) short short8;
typedef __attribute__((ext_vector_type(4))) float f32x4;

static __device__ __forceinline__ unsigned short f2bf(float f) {
  union { float f; unsigned int u; } v; v.f = f;
  unsigned int r = v.u + 0x7fffu + ((v.u >> 16) & 1u);  // round-nearest-even
  return (unsigned short)(r >> 16);
}
static __device__ __forceinline__ float bf2f(unsigned short b) {
  union { unsigned int u; float f; } v; v.u = ((unsigned int)b) << 16;
  return v.f;
}

__global__ void gate_max_kernel(const float* __restrict__ gate,
                                unsigned int* __restrict__ m_out, int E) {
  float v = 0.0f;
  for (int i = blockIdx.x * blockDim.x + threadIdx.x; i < E;
       i += gridDim.x * blockDim.x)
    v = fmaxf(v, gate[i]);
#pragma unroll
  for (int off = 32; off > 0; off >>= 1)
    v = fmaxf(v, __shfl_down(v, off, 64));
  __shared__ float smax[4];
  int lane = threadIdx.x & 63, w = threadIdx.x >> 6;
  if (lane == 0) smax[w] = v;
  __syncthreads();
  if (threadIdx.x == 0) {
    float bm = fmaxf(fmaxf(smax[0], smax[1]), fmaxf(smax[2], smax[3]));
    if (bm > 0.0f) atomicMax(m_out, __float_as_uint(bm));  // uint order==float order for >0
  }
}

__global__ void edge_exp_kernel(const float* __restrict__ gate,
                                const int* __restrict__ idx,
                                const float* __restrict__ m_ptr,
                                float* __restrict__ exp_e,
                                float* __restrict__ row_sum,
                                int* __restrict__ deg_src,
                                int* __restrict__ deg_dst, int E) {
  int e = blockIdx.x * blockDim.x + threadIdx.x;
  if (e >= E) return;
  float m = *m_ptr;
  float v = expf(gate[e] - m);
  exp_e[e] = v;
  int s = idx[2 * e], d = idx[2 * e + 1];
  atomicAdd(&row_sum[s], v);
  atomicAdd(&deg_src[s], 1);
  atomicAdd(&deg_dst[d], 1);
}

// Phase 1: per-block exclusive scan (1024 elems/block) + block sums.
__global__ __launch_bounds__(1024) void scan_part_kernel(
    const int* __restrict__ degA, const int* __restrict__ degB,
    int* __restrict__ offA, int* __restrict__ offB, int* __restrict__ sumsA,
    int* __restrict__ sumsB, int n) {
  __shared__ int tA[1024], tB[1024];
  int b = blockIdx.x, t = threadIdx.x;
  int i = b * 1024 + t;
  int vA = (i < n) ? degA[i] : 0;
  int vB = (i < n) ? degB[i] : 0;
  tA[t] = vA;
  tB[t] = vB;
  __syncthreads();
  for (int off = 1; off < 1024; off <<= 1) {
    int xA = (t >= off) ? tA[t - off] : 0;
    int xB = (t >= off) ? tB[t - off] : 0;
    __syncthreads();
    tA[t] += xA;
    tB[t] += xB;
    __syncthreads();
  }
  if (i < n) {
    offA[i] = tA[t] - vA;  // block-local exclusive
    offB[i] = tB[t] - vB;
  }
  if (t == 1023) {
    sumsA[b] = tA[t];
    sumsB[b] = tB[t];
  }
}

// Phase 2: add carry of preceding blocks (nb <= ~64, serial sum is trivial).
__global__ __launch_bounds__(1024) void scan_fixup_kernel(
    int* __restrict__ offA, int* __restrict__ offB,
    const int* __restrict__ sumsA, const int* __restrict__ sumsB, int n,
    int nb) {
  __shared__ int cA, cB;
  int b = blockIdx.x, t = threadIdx.x;
  if (t == 0) {
    int ca = 0, cb = 0;
    for (int j = 0; j < b; ++j) {
      ca += sumsA[j];
      cb += sumsB[j];
    }
    cA = ca;
    cB = cb;
  }
  __syncthreads();
  int i = b * 1024 + t;
  if (i < n) {
    offA[i] += cA;
    offB[i] += cB;
  }
  if (b == nb - 1 && t == 0) {
    offA[n] = cA + sumsA[b];
    offB[n] = cB + sumsB[b];
  }
}

__global__ void scatter_ids_kernel(const int* __restrict__ idx,
                                   const int* __restrict__ off_src,
                                   const int* __restrict__ off_dst,
                                   int* __restrict__ cur_src,
                                   int* __restrict__ cur_dst,
                                   int* __restrict__ csr_src,
                                   int* __restrict__ csr_dst, int E) {
  int e = blockIdx.x * blockDim.x + threadIdx.x;
  if (e >= E) return;
  int s = idx[2 * e], d = idx[2 * e + 1];
  int p = atomicAdd(&cur_src[s], 1);
  csr_src[off_src[s] + p] = e;
  int q = atomicAdd(&cur_dst[d], 1);
  csr_dst[off_dst[d] + q] = e;
}

// out[n*K+k] = bf16(in[k*N+n])  (weight transpose+convert, tiny)
__global__ void convt_kernel(const float* __restrict__ in,
                             short* __restrict__ out, int K, int N) {
  int i = blockIdx.x * 256 + threadIdx.x;
  if (i >= K * N) return;
  int n = i / K, k = i - n * K;
  out[i] = (short)f2bf(in[(size_t)k * N + n]);
}

// One wave per node, bf16 Mfeat gathers (ushort4/lane = 512B/row), bf16 msg out.
__global__ __launch_bounds__(256) void aggregate_kernel(
    const int* __restrict__ idx, const float* __restrict__ exp_e,
    const float* __restrict__ row_sum, const int* __restrict__ off_src,
    const int* __restrict__ csr_src, const int* __restrict__ off_dst,
    const int* __restrict__ csr_dst, const unsigned short* __restrict__ Mfeat,
    unsigned short* __restrict__ msg, int Nn) {
  int node = blockIdx.x * 4 + (threadIdx.x >> 6);
  if (node >= Nn) return;
  int lane = threadIdx.x & 63;
  float a0x = 0.f, a0y = 0.f, a0z = 0.f, a0w = 0.f;
  float a1x = 0.f, a1y = 0.f, a1z = 0.f, a1w = 0.f;
  float inv = 1.0f / (row_sum[node] + 1e-6f);
  int b0 = off_src[node], e0 = off_src[node + 1];
  for (int base = b0; base < e0; base += 64) {
    int cnt = min(64, e0 - base);
    int eid = (lane < cnt) ? csr_src[base + lane] : 0;
    float aw = (lane < cnt) ? exp_e[eid] : 0.0f;
    int oth = (lane < cnt) ? idx[2 * eid + 1] : 0;
    for (int t = 0; t < cnt; ++t) {
      float a = __shfl(aw, t, 64) * inv;
      int row = __shfl(oth, t, 64);
      ushort4 mv = *((const ushort4*)(Mfeat + (size_t)row * 256) + lane);
      a0x = fmaf(a, bf2f(mv.x), a0x);
      a0y = fmaf(a, bf2f(mv.y), a0y);
      a0z = fmaf(a, bf2f(mv.z), a0z);
      a0w = fmaf(a, bf2f(mv.w), a0w);
    }
  }
  int b1 = off_dst[node], e1 = off_dst[node + 1];
  for (int base = b1; base < e1; base += 64) {
    int cnt = min(64, e1 - base);
    int eid = (lane < cnt) ? csr_dst[base + lane] : 0;
    int s = (lane < cnt) ? idx[2 * eid] : 0;
    float aw = (lane < cnt) ? (exp_e[eid] / (row_sum[s] + 1e-6f)) : 0.0f;
    for (int t = 0; t < cnt; ++t) {
      float a = __shfl(aw, t, 64);
      int row = __shfl(s, t, 64);
      ushort4 mv = *((const ushort4*)(Mfeat + (size_t)row * 256) + lane);
      a1x = fmaf(a, bf2f(mv.x), a1x);
      a1y = fmaf(a, bf2f(mv.y), a1y);
      a1z = fmaf(a, bf2f(mv.z), a1z);
      a1w = fmaf(a, bf2f(mv.w), a1w);
    }
  }
  ushort4 o0, o1;
  o0.x = f2bf(a0x); o0.y = f2bf(a0y); o0.z = f2bf(a0z); o0.w = f2bf(a0w);
  o1.x = f2bf(a1x); o1.y = f2bf(a1y); o1.z = f2bf(a1z); o1.w = f2bf(a1w);
  *((ushort4*)(msg + (size_t)node * 512) + lane) = o0;
  *((ushort4*)(msg + (size_t)node * 512 + 256) + lane) = o1;
}

// bf16 MFMA GEMM: C[M,N] = A[M,K] @ Bt[N,K]^T + bias.
// Tile 128x64, BK=64, 256 threads = 4 waves (2x2), wave tile 64x32,
// 16x16x32 MFMA, XOR-swizzled LDS (T2).
template <int ABF16, int OUT_MODE>
__global__ __launch_bounds__(256) void mfma_gemm_kernel(
    const void* __restrict__ Av, const short* __restrict__ Bt,
    const float* __restrict__ bias, const float* __restrict__ row_sum,
    void* __restrict__ Cv, int M, int N, int K) {
  __shared__ short As[128 * 64];
  __shared__ short Bs[64 * 64];
  int tid = threadIdx.x;
  int lane = tid & 63, wid = tid >> 6;
  int wr = wid >> 1, wc = wid & 1;
  int m0 = blockIdx.x * 128, n0 = blockIdx.y * 64;

  f32x4 acc[4][2];
#pragma unroll
  for (int m = 0; m < 4; ++m)
#pragma unroll
    for (int n = 0; n < 2; ++n) acc[m][n] = (f32x4){0.f, 0.f, 0.f, 0.f};

  int ar = tid >> 1;
  int akg = (tid & 1) * 4;
  bool arow_ok = (m0 + ar) < M;
  int nr = tid >> 2;
  int nkg = (tid & 3) * 2;

  for (int k0 = 0; k0 < K; k0 += 64) {
    if (ABF16) {
      const short8* ap =
          (const short8*)((const short*)Av + (size_t)(m0 + ar) * K + k0 + akg * 8);
#pragma unroll
      for (int g2 = 0; g2 < 4; ++g2) {
        short8 w = (short8){0, 0, 0, 0, 0, 0, 0, 0};
        if (arow_ok) w = ap[g2];
        int g = akg + g2;
        *(short8*)&As[ar * 64 + ((g ^ (ar & 7)) << 3)] = w;
      }
    } else {
      const float4* ap =
          (const float4*)((const float*)Av + (size_t)(m0 + ar) * K + k0 + akg * 8);
#pragma unroll
      for (int g2 = 0; g2 < 4; ++g2) {
        float4 u = make_float4(0.f, 0.f, 0.f, 0.f);
        float4 v = make_float4(0.f, 0.f, 0.f, 0.f);
        if (arow_ok) { u = ap[2 * g2]; v = ap[2 * g2 + 1]; }
        short8 w;
        w[0] = (short)f2bf(u.x); w[1] = (short)f2bf(u.y);
        w[2] = (short)f2bf(u.z); w[3] = (short)f2bf(u.w);
        w[4] = (short)f2bf(v.x); w[5] = (short)f2bf(v.y);
        w[6] = (short)f2bf(v.z); w[7] = (short)f2bf(v.w);
        int g = akg + g2;
        *(short8*)&As[ar * 64 + ((g ^ (ar & 7)) << 3)] = w;
      }
    }
    {
      const short8* bp = (const short8*)(Bt + (size_t)(n0 + nr) * K + k0);
#pragma unroll
      for (int g2 = 0; g2 < 2; ++g2) {
        int g = nkg + g2;
        short8 w = bp[g];
        *(short8*)&Bs[nr * 64 + ((g ^ (nr & 7)) << 3)] = w;
      }
    }
    __syncthreads();
    int lsw = lane & 7, l15 = lane & 15, lk = lane >> 4;
#pragma unroll
    for (int kk = 0; kk < 2; ++kk) {
      int gg = kk * 4 + lk;
      int xo = ((gg ^ lsw) << 3);
      short8 af[4], bf[2];
#pragma unroll
      for (int m = 0; m < 4; ++m)
        af[m] = *(const short8*)&As[(wr * 64 + m * 16 + l15) * 64 + xo];
#pragma unroll
      for (int n = 0; n < 2; ++n)
        bf[n] = *(const short8*)&Bs[(wc * 32 + n * 16 + l15) * 64 + xo];
#pragma unroll
      for (int m = 0; m < 4; ++m)
#pragma unroll
        for (int n = 0; n < 2; ++n)
          acc[m][n] = __builtin_amdgcn_mfma_f32_16x16x32_bf16(af[m], bf[n],
                                                              acc[m][n], 0, 0, 0);
    }
    __syncthreads();
  }
#pragma unroll
  for (int m = 0; m < 4; ++m) {
    int gmBase = m0 + wr * 64 + m * 16 + (lane >> 4) * 4;
#pragma unroll
    for (int n = 0; n < 2; ++n) {
      int gn = n0 + wc * 32 + n * 16 + (lane & 15);
      float bv = bias[gn];
#pragma unroll
      for (int r = 0; r < 4; ++r) {
        int gm = gmBase + r;
        if (gm >= M) continue;
        float v = acc[m][n][r] + bv;
        if (OUT_MODE == 1) v = (row_sum[gm] > 0.0f) ? fmaxf(v, 0.0f) : 0.0f;
        if (OUT_MODE == 2)
          ((unsigned short*)Cv)[(size_t)gm * N + gn] = f2bf(v);
        else
          ((float*)Cv)[(size_t)gm * N + gn] = v;
      }
    }
  }
}

// LN(+relu): one wave per node, 2 features/lane, shuffle butterfly, no LDS.
__global__ __launch_bounds__(256) void ln_relu_kernel(
    const float* __restrict__ h1, const float* __restrict__ gamma,
    const float* __restrict__ beta, unsigned short* __restrict__ h1ln,
    int Nn) {
  int node = blockIdx.x * 4 + (threadIdx.x >> 6);
  if (node >= Nn) return;
  int lane = threadIdx.x & 63;
  float2 x = *((const float2*)(h1 + (size_t)node * 128) + lane);
  float s1 = x.x + x.y;
  float s2 = x.x * x.x + x.y * x.y;
#pragma unroll
  for (int off = 32; off > 0; off >>= 1) {
    s1 += __shfl_xor(s1, off, 64);
    s2 += __shfl_xor(s2, off, 64);
  }
  float mu = s1 * 0.0078125f;
  float var = s2 * 0.0078125f - mu * mu;
  float rs = rsqrtf(var + 1e-5f);
  float2 g = *((const float2*)gamma + lane);
  float2 be = *((const float2*)beta + lane);
  float y0 = (x.x - mu) * rs * g.x + be.x;
  float y1 = (x.y - mu) * rs * g.y + be.y;
  ushort2 o;
  o.x = f2bf(fmaxf(y0, 0.0f));
  o.y = f2bf(fmaxf(y1, 0.0f));
  *((ushort2*)(h1ln + (size_t)node * 128) + lane) = o;
}

extern "C" void kernel_launch(void* const* d_in, const int* in_sizes, int n_in,
                              void* d_out, int out_size, void* d_ws,
                              size_t ws_size, hipStream_t stream) {
  const float* src_feat = (const float*)d_in[0];
  const float* gate = (const float*)d_in[1];
  const int* idx = (const int*)d_in[2];
  const float* Wm = (const float*)d_in[3];
  const float* bm = (const float*)d_in[4];
  const float* W1 = (const float*)d_in[5];
  const float* b1 = (const float*)d_in[6];
  const float* gamma = (const float*)d_in[7];
  const float* beta = (const float*)d_in[8];
  const float* W2 = (const float*)d_in[9];
  const float* b2 = (const float*)d_in[10];
  float* out = (float*)d_out;

  const int D = 512;
  const int Nn = in_sizes[0] / D;  // 20000
  const int E = in_sizes[1];       // 200000

  char* ws = (char*)d_ws;
  size_t off = 0;
  auto alloc = [&](size_t bytes) {
    void* p = ws + off;
    off = (off + bytes + 255) & ~(size_t)255;
    return p;
  };
  unsigned int* m_ptr = (unsigned int*)alloc(4);
  float* exp_e = (float*)alloc((size_t)E * 4);
  float* row_sum = (float*)alloc((size_t)Nn * 4);
  unsigned short* Mfeat = (unsigned short*)alloc((size_t)Nn * 256 * 2);
  unsigned short* msg = (unsigned short*)alloc((size_t)Nn * 512 * 2);
  float* h1 = (float*)alloc((size_t)Nn * 128 * 4);
  unsigned short* h1ln = (unsigned short*)alloc((size_t)Nn * 128 * 2);
  short* WmT = (short*)alloc((size_t)512 * 256 * 2);
  short* W1T = (short*)alloc((size_t)512 * 128 * 2);
  short* W2T = (short*)alloc((size_t)128 * 512 * 2);

  // CSR scratch overlaid on h1 (consumed by aggregate before GEMM2 writes h1).
  char* ov = (char*)h1;
  size_t ooff = 0;
  auto oalloc = [&](size_t bytes) {
    void* p = ov + ooff;
    ooff = (ooff + bytes + 255) & ~(size_t)255;
    return p;
  };
  int* deg_src = (int*)oalloc((size_t)Nn * 4);
  int* deg_dst = (int*)oalloc((size_t)Nn * 4);
  int* off_src = (int*)oalloc((size_t)(Nn + 1) * 4);
  int* off_dst = (int*)oalloc((size_t)(Nn + 1) * 4);
  int* cur_src = (int*)oalloc((size_t)Nn * 4);
  int* cur_dst = (int*)oalloc((size_t)Nn * 4);
  int* csr_src = (int*)oalloc((size_t)E * 4);
  int* csr_dst = (int*)oalloc((size_t)E * 4);
  int* sumsA = (int*)oalloc(64 * 4);
  int* sumsB = (int*)oalloc(64 * 4);

  hipMemsetAsync(m_ptr, 0, 4, stream);
  hipMemsetAsync(row_sum, 0, (size_t)Nn * 4, stream);
  hipMemsetAsync(deg_src, 0, (size_t)Nn * 4, stream);
  hipMemsetAsync(deg_dst, 0, (size_t)Nn * 4, stream);
  hipMemsetAsync(cur_src, 0, (size_t)Nn * 4, stream);
  hipMemsetAsync(cur_dst, 0, (size_t)Nn * 4, stream);

  convt_kernel<<<(512 * 256 + 255) / 256, 256, 0, stream>>>(Wm, WmT, 512, 256);
  convt_kernel<<<(512 * 128 + 255) / 256, 256, 0, stream>>>(W1, W1T, 512, 128);
  convt_kernel<<<(128 * 512 + 255) / 256, 256, 0, stream>>>(W2, W2T, 128, 512);

  gate_max_kernel<<<208, 256, 0, stream>>>(gate, m_ptr, E);
  edge_exp_kernel<<<(E + 255) / 256, 256, 0, stream>>>(
      gate, idx, (const float*)m_ptr, exp_e, row_sum, deg_src, deg_dst, E);
  int nb = (Nn + 1023) / 1024;  // 20
  scan_part_kernel<<<nb, 1024, 0, stream>>>(deg_src, deg_dst, off_src, off_dst,
                                            sumsA, sumsB, Nn);
  scan_fixup_kernel<<<nb, 1024, 0, stream>>>(off_src, off_dst, sumsA, sumsB,
                                             Nn, nb);
  scatter_ids_kernel<<<(E + 255) / 256, 256, 0, stream>>>(
      idx, off_src, off_dst, cur_src, cur_dst, csr_src, csr_dst, E);

  int gx = (Nn + 127) / 128;  // 157
  // GEMM1: Mfeat(bf16) = src_feat(f32) @ Wm + bm   [M=Nn, N=256, K=512]
  mfma_gemm_kernel<0, 2><<<dim3(gx, 4), 256, 0, stream>>>(
      src_feat, WmT, bm, nullptr, Mfeat, Nn, 256, D);
  aggregate_kernel<<<(Nn + 3) / 4, 256, 0, stream>>>(
      idx, exp_e, row_sum, off_src, csr_src, off_dst, csr_dst, Mfeat, msg, Nn);
  // GEMM2: h1(f32) = msg(bf16) @ W1 + b1   [M=Nn, N=128, K=512]
  mfma_gemm_kernel<1, 0><<<dim3(gx, 2), 256, 0, stream>>>(
      msg, W1T, b1, nullptr, h1, Nn, 128, D);
  ln_relu_kernel<<<(Nn + 3) / 4, 256, 0, stream>>>(h1, gamma, beta, h1ln, Nn);
  // GEMM3: out(f32) = h1ln(bf16) @ W2 + b2, relu+mask   [M=Nn, N=512, K=128]
  mfma_gemm_kernel<1, 1><<<dim3(gx, 8), 256, 0, stream>>>(
      h1ln, W2T, b2, row_sum, out, Nn, 512, 128);
}